// Round 10
// baseline (144.080 us; speedup 1.0000x reference)
//
#include <hip/hip_runtime.h>
#include <cfloat>
#include <climits>

#define NB 16
#define NC 32
#define NZ 48
#define NY 48
#define YZ 2304             // NY*NZ
#define XYZ 110592          // 48^3
#define Q (XYZ/4)           // 27648 float4 per (b,c)
#define SUM_NUM 56623104.0  // 16*32*110592
#define TPB 256
#define VPB 1024            // voxels per block (256 thr x 4)
#define PBS 108             // blocks per sample
#define GRID (NB*PBS)       // 1728
#define CHK 8
#define NRND (NC/CHK)       // 4

struct BP {
  float s0[NC], sx[NC], sy[NC], mx[NC];
  int   mi[NC];
  float A, B, vs, q2;
};
struct Ws { BP bp[GRID]; };

#define TOP2(m1, m2, x) do { \
    if ((x) > (m1)) { (m2) = (m1); (m1) = (x); } \
    else if ((x) > (m2)) (m2) = (x); \
  } while (0)

// Single pass over the tensor. Per chunk of 8 channels: each thread loads
// and immediately consumes 8 float4 (nothing lives across barriers except
// scalars), writes per-channel (s, max) to LDS rows; a 2-level LDS
// transpose-reduce produces per-(block,channel) moments. x,y weights are
// recomputed from the row id by the reducer (rows -> voxels is affine), so
// only 2 values per channel cross the LDS, not 5.
__global__ __launch_bounds__(256) void k_main(const float* __restrict__ f,
                                              Ws* __restrict__ ws) {
  const int bb = blockIdx.x / PBS;
  const int pb = blockIdx.x - bb * PBS;
  const int t  = threadIdx.x;
  const int g0 = pb * VPB;                    // block's voxel base in sample
  const int g  = g0 + t * 4;
  const float* __restrict__ p = f + (size_t)bb * NC * XYZ + g;

  __shared__ float sbS[TPB][CHK+1];           // 9.2 KB
  __shared__ float sbM[TPB][CHK+1];           // 9.2 KB
  __shared__ unsigned sj[TPB];                // 1 KB
  __shared__ float pc3[32][CHK][3];           // 3 KB
  __shared__ float pcv[32][CHK];              // 1 KB
  __shared__ int   pct[32][CHK];              // 1 KB
  __shared__ float rr[4][4];

  const float xf = (float)(g / YZ);
  const float yf = (float)((g / NZ) % NY);    // thread's 4 voxels share (x,y)
  const float r2 = xf * xf + yf * yf;

  // persistent per-thread scalars only
  float m1x=-FLT_MAX, m1y=-FLT_MAX, m1z=-FLT_MAX, m1w=-FLT_MAX;
  float m2x=-FLT_MAX, m2y=-FLT_MAX, m2z=-FLT_MAX, m2w=-FLT_MAX;
  float qsx=0.f, qsy=0.f, qsz=0.f, qsw=0.f;
  float vsum=0.f, q2a=0.f;

  BP* bp = &ws->bp[blockIdx.x];

  for (int r = 0; r < NRND; ++r) {
    // ---- stats: 8 channels, load->consume immediately ----
    unsigned jp = 0u;
    float chunkS0 = 0.f;
    const float* pr = p + (size_t)(CHK * r) * XYZ;
#pragma unroll
    for (int k = 0; k < CHK; ++k) {
      const float4 v = *reinterpret_cast<const float4*>(pr + (size_t)k * XYZ);
      const float qx = v.x*v.x, qy = v.y*v.y, qz = v.z*v.z, qw = v.w*v.w;
      qsx += qx; qsy += qy; qsz += qz; qsw += qw;
      vsum += (v.x + v.y) + (v.z + v.w);
      const float s = (qx + qy) + (qz + qw);
      chunkS0 += s;
      float m = v.x; int e = 0;               // strict '>': first index wins
      if (v.y > m) { m = v.y; e = 1; }
      if (v.z > m) { m = v.z; e = 2; }
      if (v.w > m) { m = v.w; e = 3; }
      jp |= (unsigned)e << (2 * k);
      sbS[t][k] = s; sbM[t][k] = m;
      TOP2(m1x, m2x, v.x);
      TOP2(m1y, m2y, v.y);
      TOP2(m1z, m2z, v.z);
      TOP2(m1w, m2w, v.w);
    }
    sj[t] = jp;
    q2a = fmaf(chunkS0, r2, q2a);
    __syncthreads();                          // rows ready

    // ---- level 1: 32 row-groups x 8 channels ----
    {
      const int cc = t & 7, chg = t >> 3;
      float a0 = 0.f, a1 = 0.f, a2 = 0.f, bm = -FLT_MAX; int bt = 0;
#pragma unroll
      for (int j = 0; j < 8; ++j) {
        const int row = chg * 8 + j;          // ascending row = ascending voxel
        const int gr  = g0 + row * 4;
        const float xr = (float)(gr / YZ);
        const float yr = (float)((gr / NZ) % NY);
        const float s  = sbS[row][cc];
        a0 += s;
        a1 = fmaf(s, xr, a1);
        a2 = fmaf(s, yr, a2);
        const float vm = sbM[row][cc];
        if (vm > bm) { bm = vm; bt = row; }
      }
      pc3[chg][cc][0] = a0; pc3[chg][cc][1] = a1; pc3[chg][cc][2] = a2;
      pcv[chg][cc] = bm; pct[chg][cc] = bt;
    }
    __syncthreads();                          // partials ready

    // ---- level 2: 8 threads, one channel each ----
    if (t < CHK) {
      float b0 = 0.f, b1 = 0.f, b2 = 0.f, bm = -FLT_MAX; int brow = 0;
      for (int pp = 0; pp < 32; ++pp) {       // ascending keeps first on ties
        b0 += pc3[pp][t][0]; b1 += pc3[pp][t][1]; b2 += pc3[pp][t][2];
        const float vm = pcv[pp][t];
        if (vm > bm) { bm = vm; brow = pct[pp][t]; }
      }
      const int c = CHK * r + t;
      const int e = (int)((sj[brow] >> (2 * t)) & 3u);
      bp->s0[c] = b0; bp->sx[c] = b1; bp->sy[c] = b2;
      bp->mx[c] = bm; bp->mi[c] = g0 + brow * 4 + e;
    }
    // next chunk's row-writes only happen after its own first barrier-free
    // stats phase; sbS/sbM readers (level 1) finished before barrier #2, and
    // pc3 consumers (level 2, t<8) finish before they reach the next sync.
  }

  // ---- per-voxel div moments from global top-2 ----
  float A = 0.f, Bv = 0.f;
  {
    float q, rst;
    q = m1x*m1x; rst = qsx - q; A += q*rst + m2x*m2x*q; Bv += m1x*rst + m2x*q;
    q = m1y*m1y; rst = qsy - q; A += q*rst + m2y*m2y*q; Bv += m1y*rst + m2y*q;
    q = m1z*m1z; rst = qsz - q; A += q*rst + m2z*m2z*q; Bv += m1z*rst + m2z*q;
    q = m1w*m1w; rst = qsw - q; A += q*rst + m2w*m2w*q; Bv += m1w*rst + m2w*q;
  }
  for (int off = 32; off > 0; off >>= 1) {
    A    += __shfl_down(A,    off);
    Bv   += __shfl_down(Bv,   off);
    vsum += __shfl_down(vsum, off);
    q2a  += __shfl_down(q2a,  off);
  }
  const int w = t >> 6, l = t & 63;
  if (l == 0) { rr[w][0] = A; rr[w][1] = Bv; rr[w][2] = vsum; rr[w][3] = q2a; }
  __syncthreads();
  if (t == 0) {
    bp->A  = (rr[0][0]+rr[1][0]) + (rr[2][0]+rr[3][0]);
    bp->B  = (rr[0][1]+rr[1][1]) + (rr[2][1]+rr[3][1]);
    bp->vs = (rr[0][2]+rr[1][2]) + (rr[2][2]+rr[3][2]);
    bp->q2 = (rr[0][3]+rr[1][3]) + (rr[2][3]+rr[3][3]);
  }
}

// ---- finalize (verified round 5): merge 108 partials per (b,c), f64 ----
__global__ __launch_bounds__(512) void k_fin(const Ws* __restrict__ ws,
                                             float* __restrict__ out) {
  const int t = threadIdx.x;
  const int b = t >> 5, c = t & 31;
  double s0 = 0, sx = 0, sy = 0;
  float mv = -FLT_MAX; int mi = INT_MAX;
  for (int k = 0; k < PBS; ++k) {
    const BP* p = &ws->bp[b * PBS + k];
    s0 += p->s0[c]; sx += p->sx[c]; sy += p->sy[c];
    const float ov = p->mx[c]; const int oi = p->mi[c];
    if (ov > mv || (ov == mv && oi < mi)) { mv = ov; mi = oi; }
  }
  const double mx = (double)(mi / YZ);
  const double my = (double)((mi / NZ) % NY);
  const double mz = (double)(mi % NZ);
  double dis = (mx*mx + my*my) * s0 - 2.0*mx*sx - 2.0*my*sy
             + 2304.0 * (48.0*mz*mz - 2256.0*mz + 35720.0);
  double s0t = s0, a = 0.0, bb2 = 0.0, vsm = 0.0, q2 = 0.0;
  for (int i = t; i < GRID; i += 512) {
    a += ws->bp[i].A; bb2 += ws->bp[i].B; vsm += ws->bp[i].vs; q2 += ws->bp[i].q2;
  }
  for (int off = 32; off > 0; off >>= 1) {
    dis += __shfl_down(dis, off);
    s0t += __shfl_down(s0t, off);
    a   += __shfl_down(a,   off);
    bb2 += __shfl_down(bb2, off);
    vsm += __shfl_down(vsm, off);
    q2  += __shfl_down(q2,  off);
  }
  __shared__ double sd[8][6];
  const int wid = t >> 6;
  if ((t & 63) == 0) {
    sd[wid][0]=dis; sd[wid][1]=s0t; sd[wid][2]=a;
    sd[wid][3]=bb2; sd[wid][4]=vsm; sd[wid][5]=q2;
  }
  __syncthreads();
  if (t == 0) {
    for (int q = 1; q < 8; ++q) {
      dis += sd[q][0]; s0t += sd[q][1]; a += sd[q][2];
      bb2 += sd[q][3]; vsm += sd[q][4]; q2 += sd[q][5];
    }
    const double mgr = vsm / SUM_NUM;
    out[0] = (float)((dis + q2) / SUM_NUM);
    out[1] = (float)((a - 2.0*mgr*bb2 + mgr*mgr*s0t) / SUM_NUM);
  }
}

extern "C" void kernel_launch(void* const* d_in, const int* in_sizes, int n_in,
                              void* d_out, int out_size, void* d_ws, size_t ws_size,
                              hipStream_t stream) {
  const float* f = (const float*)d_in[0];
  Ws* ws = (Ws*)d_ws;
  float* out = (float*)d_out;
  hipLaunchKernelGGL(k_main, dim3(GRID), dim3(TPB), 0, stream, f, ws);
  hipLaunchKernelGGL(k_fin,  dim3(1),    dim3(512), 0, stream, ws, out);
}